// Round 1
// baseline (591.596 us; speedup 1.0000x reference)
//
#include <hip/hip_runtime.h>

// CausalSelfAttention: x[4,2048,1024] fp32 -> out fp32
// Pipeline (all bf16 MFMA, fp32 accum):
//  1) cvt x -> bf16            2) transpose+cvt W_attn, W_proj -> bf16 [N][K]
//  3) gemm_bt(x, W_attnT) + bias -> scatter to Q,K,V [B,H,S,D] bf16
//  4) flash attention (16x16x32 MFMA, online softmax) -> Y [B,S,E] bf16
//  5) gemm_bt(Y, W_projT) + bias -> out fp32
// MFMA 16x16x32 bf16 layouts (HW-verified per guide):
//   A: a[j] = A[m=lane&15][k=quad*8+j]  (quad=lane>>4)
//   B: b[j] = B[k=quad*8+j][n=lane&15]
//   C/D: c[i] = D[row=quad*4+i][col=lane&15]

#define BATCH 4
#define SEQ   2048
#define EMB   1024
#define NH    16
#define HD    64

typedef __bf16 bf16;
typedef __bf16 bf16x8 __attribute__((ext_vector_type(8)));
typedef float  f32x4  __attribute__((ext_vector_type(4)));
typedef unsigned int u32x4 __attribute__((ext_vector_type(4)));

// ---------------- convert fp32 -> bf16 ----------------
__global__ void cvt_f32_bf16(const float* __restrict__ in, bf16* __restrict__ out, int n) {
  int i = (blockIdx.x * blockDim.x + threadIdx.x) * 4;
  if (i + 3 < n) {
    float4 v = *(const float4*)(in + i);
    bf16 o0 = (bf16)v.x, o1 = (bf16)v.y, o2 = (bf16)v.z, o3 = (bf16)v.w;
    out[i] = o0; out[i+1] = o1; out[i+2] = o2; out[i+3] = o3;
  }
}

// ---------------- transpose + convert: W[K][N] fp32 -> WT[N][K] bf16 ----------------
__global__ void transpose_cvt(const float* __restrict__ W, bf16* __restrict__ WT,
                              int K, int N) {
  __shared__ float tile[32][33];
  int n0 = blockIdx.x * 32, k0 = blockIdx.y * 32;
  int tx = threadIdx.x & 31, ty = threadIdx.x >> 5; // ty: 0..7
#pragma unroll
  for (int r = 0; r < 4; r++) {
    int k = k0 + ty + r * 8;
    tile[ty + r * 8][tx] = W[(long)k * N + n0 + tx];
  }
  __syncthreads();
#pragma unroll
  for (int r = 0; r < 4; r++) {
    int n = n0 + ty + r * 8;
    WT[(long)n * K + k0 + tx] = (bf16)tile[tx][ty + r * 8];
  }
}

// ---------------- GEMM: A[M][K] bf16 x Bt[N][K] bf16 -> (bias add) epilogue ----------------
// 128x128 block tile, BK=32, 4 waves each 64x64 (4x4 frags of 16x16x32).
#define BM 128
#define BN 128
#define BK 32
#define LDT 40   // padded LDS k-stride (elements): 80B rows -> 2-way-max bank alias

__global__ __launch_bounds__(256, 2) void gemm_bt(
    const bf16* __restrict__ A, const bf16* __restrict__ Bt,
    const float* __restrict__ bias, int Kdim, int Ncols, int mode,
    bf16* __restrict__ q, bf16* __restrict__ k, bf16* __restrict__ v,
    float* __restrict__ out)
{
  __shared__ __align__(16) bf16 Al[BM * LDT];
  __shared__ __align__(16) bf16 Bl[BN * LDT];
  int m0 = blockIdx.y * BM;
  int n0 = blockIdx.x * BN;
  int t = threadIdx.x;
  int wave = t >> 6, lane = t & 63;
  int l15 = lane & 15, quad = lane >> 4;
  int wm = (wave & 1) * 64, wn = (wave >> 1) * 64;

  f32x4 acc[4][4] = {};

  for (int kt = 0; kt < Kdim; kt += BK) {
    __syncthreads();
#pragma unroll
    for (int it = 0; it < 2; ++it) {
      int c = t + it * 256;
      int row = c >> 2, koff = (c & 3) * 8;
      *(u32x4*)(&Al[row * LDT + koff]) =
          *(const u32x4*)(&A[(long)(m0 + row) * Kdim + kt + koff]);
      *(u32x4*)(&Bl[row * LDT + koff]) =
          *(const u32x4*)(&Bt[(long)(n0 + row) * Kdim + kt + koff]);
    }
    __syncthreads();
    bf16x8 af[4], bfr[4];
#pragma unroll
    for (int i = 0; i < 4; ++i) {
      af[i]  = *(const bf16x8*)(&Al[(wm + i * 16 + l15) * LDT + quad * 8]);
      bfr[i] = *(const bf16x8*)(&Bl[(wn + i * 16 + l15) * LDT + quad * 8]);
    }
#pragma unroll
    for (int mi = 0; mi < 4; ++mi)
#pragma unroll
      for (int ni = 0; ni < 4; ++ni)
        acc[mi][ni] = __builtin_amdgcn_mfma_f32_16x16x32_bf16(af[mi], bfr[ni], acc[mi][ni], 0, 0, 0);
  }

  // epilogue
#pragma unroll
  for (int mi = 0; mi < 4; ++mi) {
#pragma unroll
    for (int ni = 0; ni < 4; ++ni) {
      int gcol = n0 + wn + ni * 16 + l15;
      float bv = bias[gcol];
#pragma unroll
      for (int i = 0; i < 4; ++i) {
        int grow = m0 + wm + mi * 16 + quad * 4 + i;
        float val = acc[mi][ni][i] + bv;
        if (mode == 0) {
          // scatter into Q/K/V [B,NH,S,HD] bf16, col = which*1024 + h*64 + d
          int which = gcol >> 10, e = gcol & 1023;
          int h = e >> 6, d = e & 63;
          int b = grow >> 11, s = grow & 2047;
          bf16* dst = (which == 0) ? q : ((which == 1) ? k : v);
          dst[(((long)b * NH + h) * SEQ + s) * HD + d] = (bf16)val;
        } else {
          out[(long)grow * Ncols + gcol] = val;
        }
      }
    }
  }
}

// ---------------- flash attention ----------------
// grid: (SEQ/64, BATCH*NH); block 256 = 4 waves; wave handles 16 q rows.
// K/V tiles of 32 keys; per tile: 4 score MFMAs + online softmax + 4 PV MFMAs.
#define LDK 72   // K_lds row stride (elems): 144B rows, 16B aligned, 2-way alias
#define LDV 40   // V_ldsT row stride
#define LDP 40   // P_lds row stride

__global__ __launch_bounds__(256, 2) void attn(
    const bf16* __restrict__ Q, const bf16* __restrict__ K,
    const bf16* __restrict__ V, bf16* __restrict__ Y)
{
  __shared__ __align__(16) bf16 Kl[32 * LDK];
  __shared__ __align__(16) bf16 Vl[64 * LDV];   // transposed: [d][key]
  __shared__ __align__(16) bf16 Pl[4][16 * LDP]; // per-wave
  int q0 = blockIdx.x * 64;
  int b = blockIdx.y >> 4, h = blockIdx.y & 15;
  const bf16* Qp = Q + (((long)b * NH + h) * SEQ) * HD;
  const bf16* Kp = K + (((long)b * NH + h) * SEQ) * HD;
  const bf16* Vp = V + (((long)b * NH + h) * SEQ) * HD;
  int t = threadIdx.x, wave = t >> 6, lane = t & 63;
  int l15 = lane & 15, quad = lane >> 4;
  int wq0 = q0 + wave * 16;

  // Q fragments (reused for all K tiles): A[m=l15][k=quad*8+j], k split 0/32
  bf16x8 qf0, qf1;
  {
    const bf16* qrow = Qp + (long)(wq0 + l15) * HD + quad * 8;
    qf0 = *(const bf16x8*)(qrow);
    qf1 = *(const bf16x8*)(qrow + 32);
  }
  float mrow[4], lrow[4];
  f32x4 oacc[4] = {};
#pragma unroll
  for (int i = 0; i < 4; ++i) { mrow[i] = -1e30f; lrow[i] = 0.f; }

  const float scale = 0.125f; // 1/sqrt(64)
  int ntiles = q0 / 32 + 2;
  int srow = t >> 3, soff = (t & 7) * 8; // staging: 32 rows x 64, 16B chunks

  for (int kt = 0; kt < ntiles; ++kt) {
    int k0 = kt * 32;
    __syncthreads();
    // stage K tile row-major [key][d], V tile transposed [d][key]
    {
      const bf16* ks = &Kp[(long)(k0 + srow) * HD + soff];
      *(u32x4*)(&Kl[srow * LDK + soff]) = *(const u32x4*)ks;
      bf16x8 vv = *(const bf16x8*)(&Vp[(long)(k0 + srow) * HD + soff]);
#pragma unroll
      for (int j = 0; j < 8; ++j) Vl[(soff + j) * LDV + srow] = vv[j];
    }
    __syncthreads();
    if (k0 <= wq0 + 15) {
      // scores: S[16q x 32k] = Q[16x64] @ K^T; two 16-col n-tiles, two k-steps
      bf16x8 k0l = *(const bf16x8*)(&Kl[l15 * LDK + quad * 8]);
      bf16x8 k0h = *(const bf16x8*)(&Kl[l15 * LDK + 32 + quad * 8]);
      bf16x8 k1l = *(const bf16x8*)(&Kl[(16 + l15) * LDK + quad * 8]);
      bf16x8 k1h = *(const bf16x8*)(&Kl[(16 + l15) * LDK + 32 + quad * 8]);
      f32x4 s0 = {}, s1 = {};
      s0 = __builtin_amdgcn_mfma_f32_16x16x32_bf16(qf0, k0l, s0, 0, 0, 0);
      s0 = __builtin_amdgcn_mfma_f32_16x16x32_bf16(qf1, k0h, s0, 0, 0, 0);
      s1 = __builtin_amdgcn_mfma_f32_16x16x32_bf16(qf0, k1l, s1, 0, 0, 0);
      s1 = __builtin_amdgcn_mfma_f32_16x16x32_bf16(qf1, k1h, s1, 0, 0, 0);
#pragma unroll
      for (int i = 0; i < 4; ++i) {
        int qr = wq0 + quad * 4 + i;
        float v0 = (k0 + l15      <= qr) ? s0[i] * scale : -1e30f;
        float v1 = (k0 + 16 + l15 <= qr) ? s1[i] * scale : -1e30f;
        float mx = fmaxf(v0, v1);
#pragma unroll
        for (int off = 8; off; off >>= 1) mx = fmaxf(mx, __shfl_xor(mx, off, 16));
        float mnew = fmaxf(mrow[i], mx);
        float a = __expf(mrow[i] - mnew);
        float e0 = __expf(v0 - mnew);
        float e1 = __expf(v1 - mnew);
        float rs = e0 + e1;
#pragma unroll
        for (int off = 8; off; off >>= 1) rs += __shfl_xor(rs, off, 16);
        lrow[i] = lrow[i] * a + rs;
        mrow[i] = mnew;
        oacc[0][i] *= a; oacc[1][i] *= a; oacc[2][i] *= a; oacc[3][i] *= a;
        Pl[wave][(quad * 4 + i) * LDP + l15]      = (bf16)e0;
        Pl[wave][(quad * 4 + i) * LDP + 16 + l15] = (bf16)e1;
      }
      asm volatile("s_waitcnt lgkmcnt(0)" ::: "memory");
      // P in A-layout: P[m=l15][k=quad*8+j]
      bf16x8 pf = *(const bf16x8*)(&Pl[wave][l15 * LDP + quad * 8]);
#pragma unroll
      for (int ni = 0; ni < 4; ++ni) {
        bf16x8 vf = *(const bf16x8*)(&Vl[(ni * 16 + l15) * LDV + quad * 8]);
        oacc[ni] = __builtin_amdgcn_mfma_f32_16x16x32_bf16(pf, vf, oacc[ni], 0, 0, 0);
      }
    }
  }
  // epilogue: Y[b][s][h*64 + d] bf16
#pragma unroll
  for (int i = 0; i < 4; ++i) {
    int qr = wq0 + quad * 4 + i;
    float inv = 1.0f / lrow[i];
    bf16* dst = Y + ((long)(b * SEQ + qr)) * EMB + h * HD;
#pragma unroll
    for (int ni = 0; ni < 4; ++ni)
      dst[ni * 16 + l15] = (bf16)(oacc[ni][i] * inv);
  }
}

extern "C" void kernel_launch(void* const* d_in, const int* in_sizes, int n_in,
                              void* d_out, int out_size, void* d_ws, size_t ws_size,
                              hipStream_t stream) {
  const float* x      = (const float*)d_in[0];
  const float* W_attn = (const float*)d_in[1];
  const float* b_attn = (const float*)d_in[2];
  const float* W_proj = (const float*)d_in[3];
  const float* b_proj = (const float*)d_in[4];
  float* out = (float*)d_out;
  char* ws = (char*)d_ws;
  // workspace layout (92.3 MB total)
  bf16* xb  = (bf16*)(ws);                 // 16.78 MB
  bf16* WaT = (bf16*)(ws + 16777216);      //  6.29 MB
  bf16* WpT = (bf16*)(ws + 23068672);      //  2.10 MB
  bf16* Qb  = (bf16*)(ws + 25165824);      // 16.78 MB
  bf16* Kb  = (bf16*)(ws + 41943040);      // 16.78 MB
  bf16* Vb  = (bf16*)(ws + 58720256);      // 16.78 MB
  bf16* Yb  = (bf16*)(ws + 75497472);      // 16.78 MB

  cvt_f32_bf16<<<8192, 256, 0, stream>>>(x, xb, BATCH * SEQ * EMB);
  transpose_cvt<<<dim3(96, 32), 256, 0, stream>>>(W_attn, WaT, EMB, 3 * EMB);
  transpose_cvt<<<dim3(32, 32), 256, 0, stream>>>(W_proj, WpT, EMB, EMB);
  gemm_bt<<<dim3(24, 64), 256, 0, stream>>>(xb, WaT, b_attn, EMB, 3 * EMB, 0,
                                            Qb, Kb, Vb, nullptr);
  attn<<<dim3(SEQ / 64, BATCH * NH), 256, 0, stream>>>(Qb, Kb, Vb, Yb);
  gemm_bt<<<dim3(8, 64), 256, 0, stream>>>(Yb, WpT, b_proj, EMB, EMB, 1,
                                           nullptr, nullptr, nullptr, out);
}

// Round 2
// 348.724 us; speedup vs baseline: 1.6965x; 1.6965x over previous
//
#include <hip/hip_runtime.h>

// CausalSelfAttention: x[4,2048,1024] fp32 -> out fp32
// Pipeline (all bf16 MFMA, fp32 accum):
//  1) cvt x -> bf16            2) transpose+cvt W_attn, W_proj -> bf16 [N][K]
//  3) gemm_bt(x, W_attnT) + bias -> scatter to Q,K,V [B,H,S,D] bf16
//  4) flash attention (64-key tiles, balanced strip pairs, swizzled LDS) -> Y bf16
//  5) gemm_bt(Y, W_projT) + bias -> out fp32
// MFMA 16x16x32 bf16 layouts (HW-verified per guide):
//   A: a[j] = A[m=lane&15][k=quad*8+j]  (quad=lane>>4)
//   B: b[j] = B[k=quad*8+j][n=lane&15]
//   C/D: c[i] = D[row=quad*4+i][col=lane&15]

#define BATCH 4
#define SEQ   2048
#define EMB   1024
#define NH    16
#define HD    64

typedef __bf16 bf16;
typedef __bf16 bf16x8 __attribute__((ext_vector_type(8)));
typedef float  f32x4  __attribute__((ext_vector_type(4)));
typedef unsigned int u32x4 __attribute__((ext_vector_type(4)));

// ---------------- convert fp32 -> bf16 ----------------
__global__ void cvt_f32_bf16(const float* __restrict__ in, bf16* __restrict__ out, int n) {
  int i = (blockIdx.x * blockDim.x + threadIdx.x) * 4;
  if (i + 3 < n) {
    float4 v = *(const float4*)(in + i);
    bf16 o0 = (bf16)v.x, o1 = (bf16)v.y, o2 = (bf16)v.z, o3 = (bf16)v.w;
    out[i] = o0; out[i+1] = o1; out[i+2] = o2; out[i+3] = o3;
  }
}

// ---------------- transpose + convert: W[K][N] fp32 -> WT[N][K] bf16 ----------------
__global__ void transpose_cvt(const float* __restrict__ W, bf16* __restrict__ WT,
                              int K, int N) {
  __shared__ float tile[32][33];
  int n0 = blockIdx.x * 32, k0 = blockIdx.y * 32;
  int tx = threadIdx.x & 31, ty = threadIdx.x >> 5; // ty: 0..7
#pragma unroll
  for (int r = 0; r < 4; r++) {
    int k = k0 + ty + r * 8;
    tile[ty + r * 8][tx] = W[(long)k * N + n0 + tx];
  }
  __syncthreads();
#pragma unroll
  for (int r = 0; r < 4; r++) {
    int n = n0 + ty + r * 8;
    WT[(long)n * K + k0 + tx] = (bf16)tile[tx][ty + r * 8];
  }
}

// ---------------- GEMM: A[M][K] bf16 x Bt[N][K] bf16 -> (bias add) epilogue ----------------
// 128x128 block tile, BK=32, 4 waves each 64x64 (4x4 frags of 16x16x32).
#define BM 128
#define BN 128
#define BK 32
#define LDT 40   // padded LDS k-stride (elements)

__global__ __launch_bounds__(256, 2) void gemm_bt(
    const bf16* __restrict__ A, const bf16* __restrict__ Bt,
    const float* __restrict__ bias, int Kdim, int Ncols, int mode,
    bf16* __restrict__ q, bf16* __restrict__ k, bf16* __restrict__ v,
    float* __restrict__ out)
{
  __shared__ __align__(16) bf16 Al[BM * LDT];
  __shared__ __align__(16) bf16 Bl[BN * LDT];
  int m0 = blockIdx.y * BM;
  int n0 = blockIdx.x * BN;
  int t = threadIdx.x;
  int wave = t >> 6, lane = t & 63;
  int l15 = lane & 15, quad = lane >> 4;
  int wm = (wave & 1) * 64, wn = (wave >> 1) * 64;

  f32x4 acc[4][4] = {};

  for (int kt = 0; kt < Kdim; kt += BK) {
    __syncthreads();
#pragma unroll
    for (int it = 0; it < 2; ++it) {
      int c = t + it * 256;
      int row = c >> 2, koff = (c & 3) * 8;
      *(u32x4*)(&Al[row * LDT + koff]) =
          *(const u32x4*)(&A[(long)(m0 + row) * Kdim + kt + koff]);
      *(u32x4*)(&Bl[row * LDT + koff]) =
          *(const u32x4*)(&Bt[(long)(n0 + row) * Kdim + kt + koff]);
    }
    __syncthreads();
    bf16x8 af[4], bfr[4];
#pragma unroll
    for (int i = 0; i < 4; ++i) {
      af[i]  = *(const bf16x8*)(&Al[(wm + i * 16 + l15) * LDT + quad * 8]);
      bfr[i] = *(const bf16x8*)(&Bl[(wn + i * 16 + l15) * LDT + quad * 8]);
    }
#pragma unroll
    for (int mi = 0; mi < 4; ++mi)
#pragma unroll
      for (int ni = 0; ni < 4; ++ni)
        acc[mi][ni] = __builtin_amdgcn_mfma_f32_16x16x32_bf16(af[mi], bfr[ni], acc[mi][ni], 0, 0, 0);
  }

  // epilogue
#pragma unroll
  for (int mi = 0; mi < 4; ++mi) {
#pragma unroll
    for (int ni = 0; ni < 4; ++ni) {
      int gcol = n0 + wn + ni * 16 + l15;
      float bv = bias[gcol];
#pragma unroll
      for (int i = 0; i < 4; ++i) {
        int grow = m0 + wm + mi * 16 + quad * 4 + i;
        float val = acc[mi][ni][i] + bv;
        if (mode == 0) {
          int which = gcol >> 10, e = gcol & 1023;
          int h = e >> 6, d = e & 63;
          int b = grow >> 11, s = grow & 2047;
          bf16* dst = (which == 0) ? q : ((which == 1) ? k : v);
          dst[(((long)b * NH + h) * SEQ + s) * HD + d] = (bf16)val;
        } else {
          out[(long)grow * Ncols + gcol] = val;
        }
      }
    }
  }
}

// ---------------- flash attention ----------------
// grid: (16, BATCH*NH); block 256 = 4 waves; each block runs TWO 64-row q-strips
// (strip i, then strip 31-i) so every block does exactly 33 compute-tiles.
// KV tiles of 64 keys; per wave per tile: 8 score MFMAs + softmax + 8 PV MFMAs.
#define LDK 72   // Kl row stride (elems); 144B rows, 16B-aligned

__global__ __launch_bounds__(256, 4) void attn(
    const bf16* __restrict__ Q, const bf16* __restrict__ K,
    const bf16* __restrict__ V, bf16* __restrict__ Y)
{
  __shared__ __align__(16) bf16 Kl[64 * LDK];          // [key][d], padded
  __shared__ __align__(16) bf16 Vl[64 * 64];           // [d][key^swz], XOR-swizzled
  __shared__ __align__(16) bf16 Pl[4][16 * 64];        // per-wave [q][col^swz]
  int b = blockIdx.y >> 4, h = blockIdx.y & 15;
  const bf16* Qp = Q + (((long)b * NH + h) * SEQ) * HD;
  const bf16* Kp = K + (((long)b * NH + h) * SEQ) * HD;
  const bf16* Vp = V + (((long)b * NH + h) * SEQ) * HD;
  int t = threadIdx.x, wave = t >> 6, lane = t & 63;
  int l15 = lane & 15, quad = lane >> 4;
  int g = t & 7, srow = t >> 3;          // staging coords: srow 0..31, g 0..7
  const float scale = 0.125f;            // 1/sqrt(64)

#pragma unroll 1
  for (int pass = 0; pass < 2; ++pass) {
    int q0 = (pass == 0) ? blockIdx.x * 64 : (SEQ - 64) - blockIdx.x * 64;
    int wq0 = q0 + wave * 16;

    // Q fragments: A[m=l15][k=quad*8+j], k split 0/32
    bf16x8 qf0, qf1;
    {
      const bf16* qrow = Qp + (long)(wq0 + l15) * HD + quad * 8;
      qf0 = *(const bf16x8*)(qrow);
      qf1 = *(const bf16x8*)(qrow + 32);
    }
    float mrow[4], lrow[4];
    f32x4 oacc[4] = {};
#pragma unroll
    for (int i = 0; i < 4; ++i) { mrow[i] = -1e30f; lrow[i] = 0.f; }

    int ntiles = q0 / 64 + 1;            // keys only up to the diagonal tile
#pragma unroll 1
    for (int kt = 0; kt < ntiles; ++kt) {
      int k0 = kt * 64;
      __syncthreads();
      // stage K [key][d] (vector), V transposed [d][key] with XOR swizzle
#pragma unroll
      for (int half = 0; half < 2; ++half) {
        int key = half * 32 + srow;
        *(u32x4*)(&Kl[key * LDK + g * 8]) =
            *(const u32x4*)(&Kp[(long)(k0 + key) * HD + g * 8]);
        bf16x8 vv = *(const bf16x8*)(&Vp[(long)(k0 + key) * HD + g * 8]);
        int kswz = key ^ (8 * g);        // d>>3 == g for all 8 elems
#pragma unroll
        for (int j = 0; j < 8; ++j) Vl[(g * 8 + j) * 64 + kswz] = vv[j];
      }
      __syncthreads();

      // scores: S[16q x 64k] = Q @ K^T  (4 n-frags x 2 k-steps)
      f32x4 s[4] = {};
#pragma unroll
      for (int kk = 0; kk < 2; ++kk) {
        bf16x8 qf = kk ? qf1 : qf0;
#pragma unroll
        for (int ni = 0; ni < 4; ++ni) {
          bf16x8 kfr = *(const bf16x8*)(&Kl[(ni * 16 + l15) * LDK + kk * 32 + quad * 8]);
          s[ni] = __builtin_amdgcn_mfma_f32_16x16x32_bf16(qf, kfr, s[ni], 0, 0, 0);
        }
      }

      bool full = (k0 + 63 <= wq0);      // wave-uniform: no masking needed
#pragma unroll
      for (int i = 0; i < 4; ++i) {
        int qr = wq0 + quad * 4 + i;
        float sv[4];
#pragma unroll
        for (int ni = 0; ni < 4; ++ni) {
          float x = s[ni][i] * scale;
          if (!full) x = (k0 + ni * 16 + l15 <= qr) ? x : -1e30f;
          sv[ni] = x;
        }
        float mx = fmaxf(fmaxf(sv[0], sv[1]), fmaxf(sv[2], sv[3]));
#pragma unroll
        for (int off = 8; off; off >>= 1) mx = fmaxf(mx, __shfl_xor(mx, off, 16));
        float mnew = fmaxf(mrow[i], mx);
        float a = __expf(mrow[i] - mnew);
        float e0 = __expf(sv[0] - mnew);
        float e1 = __expf(sv[1] - mnew);
        float e2 = __expf(sv[2] - mnew);
        float e3 = __expf(sv[3] - mnew);
        float rs = (e0 + e1) + (e2 + e3);
#pragma unroll
        for (int off = 8; off; off >>= 1) rs += __shfl_xor(rs, off, 16);
        lrow[i] = lrow[i] * a + rs;
        mrow[i] = mnew;
#pragma unroll
        for (int ni = 0; ni < 4; ++ni) oacc[ni][i] *= a;
        // P store, col' = col ^ (quad*16) -> conflict-free scalar stores
        int prow = (quad * 4 + i) * 64;
        Pl[wave][prow + (((0 ^ quad) * 16) + l15)] = (bf16)e0;
        Pl[wave][prow + (((1 ^ quad) * 16) + l15)] = (bf16)e1;
        Pl[wave][prow + (((2 ^ quad) * 16) + l15)] = (bf16)e2;
        Pl[wave][prow + (((3 ^ quad) * 16) + l15)] = (bf16)e3;
      }
      asm volatile("s_waitcnt lgkmcnt(0)" ::: "memory");
      // PV: P[16x64] @ V[64x64], 2 k-steps x 4 n-frags
#pragma unroll
      for (int kk = 0; kk < 2; ++kk) {
        int kbase = kk * 32 + quad * 8;
        bf16x8 pf = *(const bf16x8*)(&Pl[wave][l15 * 64 + (kbase ^ ((l15 >> 2) * 16))]);
#pragma unroll
        for (int ni = 0; ni < 4; ++ni) {
          int dd = ni * 16 + l15;
          bf16x8 vf = *(const bf16x8*)(&Vl[dd * 64 + (kbase ^ (8 * ((dd >> 3) & 7)))]);
          oacc[ni] = __builtin_amdgcn_mfma_f32_16x16x32_bf16(pf, vf, oacc[ni], 0, 0, 0);
        }
      }
    }
    // epilogue: Y[b][s][h*64 + d] bf16
#pragma unroll
    for (int i = 0; i < 4; ++i) {
      int qr = wq0 + quad * 4 + i;
      float inv = 1.0f / lrow[i];
      bf16* dst = Y + ((long)(b * SEQ + qr)) * EMB + h * HD;
#pragma unroll
      for (int ni = 0; ni < 4; ++ni)
        dst[ni * 16 + l15] = (bf16)(oacc[ni][i] * inv);
    }
  }
}

extern "C" void kernel_launch(void* const* d_in, const int* in_sizes, int n_in,
                              void* d_out, int out_size, void* d_ws, size_t ws_size,
                              hipStream_t stream) {
  const float* x      = (const float*)d_in[0];
  const float* W_attn = (const float*)d_in[1];
  const float* b_attn = (const float*)d_in[2];
  const float* W_proj = (const float*)d_in[3];
  const float* b_proj = (const float*)d_in[4];
  float* out = (float*)d_out;
  char* ws = (char*)d_ws;
  bf16* xb  = (bf16*)(ws);                 // 16.78 MB
  bf16* WaT = (bf16*)(ws + 16777216);      //  6.29 MB
  bf16* WpT = (bf16*)(ws + 23068672);      //  2.10 MB
  bf16* Qb  = (bf16*)(ws + 25165824);      // 16.78 MB
  bf16* Kb  = (bf16*)(ws + 41943040);      // 16.78 MB
  bf16* Vb  = (bf16*)(ws + 58720256);      // 16.78 MB
  bf16* Yb  = (bf16*)(ws + 75497472);      // 16.78 MB

  cvt_f32_bf16<<<8192, 256, 0, stream>>>(x, xb, BATCH * SEQ * EMB);
  transpose_cvt<<<dim3(96, 32), 256, 0, stream>>>(W_attn, WaT, EMB, 3 * EMB);
  transpose_cvt<<<dim3(32, 32), 256, 0, stream>>>(W_proj, WpT, EMB, EMB);
  gemm_bt<<<dim3(24, 64), 256, 0, stream>>>(xb, WaT, b_attn, EMB, 3 * EMB, 0,
                                            Qb, Kb, Vb, nullptr);
  attn<<<dim3(16, BATCH * NH), 256, 0, stream>>>(Qb, Kb, Vb, Yb);
  gemm_bt<<<dim3(8, 64), 256, 0, stream>>>(Yb, WpT, b_proj, EMB, EMB, 1,
                                           nullptr, nullptr, nullptr, out);
}

// Round 3
// 298.649 us; speedup vs baseline: 1.9809x; 1.1677x over previous
//
#include <hip/hip_runtime.h>

// CausalSelfAttention: x[4,2048,1024] fp32 -> out fp32
// Pipeline (all bf16 MFMA, fp32 accum):
//  1) cvt x -> bf16            2) transpose+cvt W_attn, W_proj -> bf16 [N][K]
//  3) gemm_bt + bias -> Q (pre-scaled by 0.125*log2e) [b,h,s,d], K [b,h,s,d],
//     V TRANSPOSED [b,h,d,s]  (all bf16)
//  4) flash attention: fixed-max softmax (P = 2^s), K/Vt staged direct-to-LDS
//     via global_load_lds w/ XOR source swizzle; P roundtrip through LDS.
//  5) gemm_bt(Y, W_projT) + bias -> out fp32
// MFMA 16x16x32 bf16 layouts (HW-verified per guide):
//   A: a[j] = A[m=lane&15][k=quad*8+j]  (quad=lane>>4)
//   B: b[j] = B[k=quad*8+j][n=lane&15]
//   C/D: c[i] = D[row=quad*4+i][col=lane&15]

#define BATCH 4
#define SEQ   2048
#define EMB   1024
#define NH    16
#define HD    64

typedef __bf16 bf16;
typedef __bf16 bf16x8 __attribute__((ext_vector_type(8)));
typedef float  f32x4  __attribute__((ext_vector_type(4)));
typedef unsigned int u32x4 __attribute__((ext_vector_type(4)));

// direct global->LDS 16B copy: LDS dest is wave-uniform base + lane*16
__device__ __forceinline__ void ld_lds16(const void* g, void* l) {
  __builtin_amdgcn_global_load_lds(
      (const __attribute__((address_space(1))) void*)g,
      (__attribute__((address_space(3))) void*)l, 16, 0, 0);
}

// ---------------- convert fp32 -> bf16 ----------------
__global__ void cvt_f32_bf16(const float* __restrict__ in, bf16* __restrict__ out, int n) {
  int i = (blockIdx.x * blockDim.x + threadIdx.x) * 4;
  if (i + 3 < n) {
    float4 v = *(const float4*)(in + i);
    bf16 o0 = (bf16)v.x, o1 = (bf16)v.y, o2 = (bf16)v.z, o3 = (bf16)v.w;
    out[i] = o0; out[i+1] = o1; out[i+2] = o2; out[i+3] = o3;
  }
}

// ---------------- transpose + convert: W[K][N] fp32 -> WT[N][K] bf16 ----------------
__global__ void transpose_cvt(const float* __restrict__ W, bf16* __restrict__ WT,
                              int K, int N) {
  __shared__ float tile[32][33];
  int n0 = blockIdx.x * 32, k0 = blockIdx.y * 32;
  int tx = threadIdx.x & 31, ty = threadIdx.x >> 5; // ty: 0..7
#pragma unroll
  for (int r = 0; r < 4; r++) {
    int k = k0 + ty + r * 8;
    tile[ty + r * 8][tx] = W[(long)k * N + n0 + tx];
  }
  __syncthreads();
#pragma unroll
  for (int r = 0; r < 4; r++) {
    int n = n0 + ty + r * 8;
    WT[(long)n * K + k0 + tx] = (bf16)tile[tx][ty + r * 8];
  }
}

// ---------------- GEMM: A[M][K] bf16 x Bt[N][K] bf16 + bias ----------------
// 128x128 tile, BK=32, direct-to-LDS staging (lane-linear, unpadded 32-elem rows).
#define QSCALE 0.18033688f   // (1/8) * log2(e): folds attn scale + exp2 conversion

__global__ __launch_bounds__(256, 2) void gemm_bt(
    const bf16* __restrict__ A, const bf16* __restrict__ Bt,
    const float* __restrict__ bias, int Kdim, int Ncols, int mode,
    bf16* __restrict__ q, bf16* __restrict__ k, bf16* __restrict__ v,
    float* __restrict__ out)
{
  __shared__ __align__(16) bf16 Al[128 * 32];
  __shared__ __align__(16) bf16 Bl[128 * 32];
  int m0 = blockIdx.y * 128;
  int n0 = blockIdx.x * 128;
  int t = threadIdx.x;
  int wave = t >> 6, lane = t & 63;
  int l15 = lane & 15, quad = lane >> 4;
  int wm = (wave & 1) * 64, wn = (wave >> 1) * 64;

  f32x4 acc[4][4] = {};

  for (int kt = 0; kt < Kdim; kt += 32) {
    __syncthreads();
#pragma unroll
    for (int it = 0; it < 2; ++it) {
      int c = it * 256 + t;                 // 16B-unit index; row=c>>2, koff=(c&3)*8
      ld_lds16(&A[(long)(m0 + (c >> 2)) * Kdim + kt + (c & 3) * 8],
               &Al[(it * 256 + wave * 64) * 8]);
      ld_lds16(&Bt[(long)(n0 + (c >> 2)) * Kdim + kt + (c & 3) * 8],
               &Bl[(it * 256 + wave * 64) * 8]);
    }
    __syncthreads();
    bf16x8 af[4], bfr[4];
#pragma unroll
    for (int i = 0; i < 4; ++i) {
      af[i]  = *(const bf16x8*)(&Al[(wm + i * 16 + l15) * 32 + quad * 8]);
      bfr[i] = *(const bf16x8*)(&Bl[(wn + i * 16 + l15) * 32 + quad * 8]);
    }
#pragma unroll
    for (int mi = 0; mi < 4; ++mi)
#pragma unroll
      for (int ni = 0; ni < 4; ++ni)
        acc[mi][ni] = __builtin_amdgcn_mfma_f32_16x16x32_bf16(af[mi], bfr[ni], acc[mi][ni], 0, 0, 0);
  }

  // epilogue
#pragma unroll
  for (int mi = 0; mi < 4; ++mi) {
#pragma unroll
    for (int ni = 0; ni < 4; ++ni) {
      int gcol = n0 + wn + ni * 16 + l15;
      float bv = bias[gcol];
#pragma unroll
      for (int i = 0; i < 4; ++i) {
        int grow = m0 + wm + mi * 16 + quad * 4 + i;
        float val = acc[mi][ni][i] + bv;
        if (mode == 0) {
          int which = gcol >> 10, e = gcol & 1023;
          int h = e >> 6, d = e & 63;
          int b = grow >> 11, s = grow & 2047;
          if (which == 0) {
            q[(((long)b * NH + h) * SEQ + s) * HD + d] = (bf16)(val * QSCALE);
          } else if (which == 1) {
            k[(((long)b * NH + h) * SEQ + s) * HD + d] = (bf16)val;
          } else {
            v[(((long)b * NH + h) * HD + d) * SEQ + s] = (bf16)val;  // V^T
          }
        } else {
          out[(long)grow * Ncols + gcol] = val;
        }
      }
    }
  }
}

// ---------------- flash attention ----------------
// grid (16, B*NH); block 256 = 4 waves; block runs strips i and 31-i (balanced).
// 64-key tiles; K and V^T staged direct-to-LDS with XOR source swizzle so the
// lane-linear layout reads conflict-balanced. Fixed-max softmax: P = 2^s
// (Q pre-scaled by 0.125*log2e), l deferred to epilogue.
__global__ __launch_bounds__(256, 4) void attn(
    const bf16* __restrict__ Q, const bf16* __restrict__ K,
    const bf16* __restrict__ Vt, bf16* __restrict__ Y)
{
  __shared__ __align__(16) bf16 Kl[64 * 64];       // [key][d], units swizzled by key&7
  __shared__ __align__(16) bf16 Vl[64 * 64];       // [d][key], units swizzled by d&7
  __shared__ __align__(16) bf16 Pl[4][16 * 64];    // per-wave [q][col^swz]
  int b = blockIdx.y >> 4, h = blockIdx.y & 15;
  const bf16* Qp  = Q  + (((long)b * NH + h) * SEQ) * HD;
  const bf16* Kp  = K  + (((long)b * NH + h) * SEQ) * HD;
  const bf16* Vtp = Vt + (((long)b * NH + h) * HD) * SEQ;
  int t = threadIdx.x, wave = t >> 6, lane = t & 63;
  int l15 = lane & 15, quad = lane >> 4;

#pragma unroll 1
  for (int pass = 0; pass < 2; ++pass) {
    int q0 = (pass == 0) ? blockIdx.x * 64 : (SEQ - 64) - blockIdx.x * 64;
    int wq0 = q0 + wave * 16;

    // Q fragments: A[m=l15][k=quad*8+j], k split 0/32 (Q pre-scaled)
    bf16x8 qf0, qf1;
    {
      const bf16* qrow = Qp + (long)(wq0 + l15) * HD + quad * 8;
      qf0 = *(const bf16x8*)(qrow);
      qf1 = *(const bf16x8*)(qrow + 32);
    }
    float lrow[4] = {0.f, 0.f, 0.f, 0.f};
    f32x4 oacc[4] = {};

    int ntiles = q0 / 64 + 1;
#pragma unroll 1
    for (int kt = 0; kt < ntiles; ++kt) {
      int k0 = kt * 64;
      __syncthreads();
      // stage K [key][d] and V^T [d][key]; source-swizzled so LDS unit
      // (row*8 + u) holds global chunk (u ^ (row&7)) of that row.
#pragma unroll
      for (int it = 0; it < 2; ++it) {
        int cu = it * 256 + t;
        int row = cu >> 3, u = cu & 7;
        ld_lds16(&Kp[(long)(k0 + row) * HD + ((u ^ (row & 7)) * 8)],
                 &Kl[(it * 256 + wave * 64) * 8]);
        ld_lds16(&Vtp[(long)row * SEQ + k0 + ((u ^ (row & 7)) * 8)],
                 &Vl[(it * 256 + wave * 64) * 8]);
      }
      __syncthreads();

      // scores: S[16q x 64k] = Q @ K^T  (4 n-frags x 2 k-steps)
      f32x4 s[4] = {};
#pragma unroll
      for (int kk = 0; kk < 2; ++kk) {
        bf16x8 qf = kk ? qf1 : qf0;
#pragma unroll
        for (int ni = 0; ni < 4; ++ni) {
          int r = ni * 16 + l15, u = kk * 4 + quad;
          bf16x8 kfr = *(const bf16x8*)(&Kl[r * 64 + ((u ^ (r & 7)) * 8)]);
          s[ni] = __builtin_amdgcn_mfma_f32_16x16x32_bf16(qf, kfr, s[ni], 0, 0, 0);
        }
      }

      bool full = (k0 + 63 <= wq0);   // wave-uniform
#pragma unroll
      for (int i = 0; i < 4; ++i) {
        int qr = wq0 + quad * 4 + i;
        float e[4];
#pragma unroll
        for (int ni = 0; ni < 4; ++ni) {
          float x = s[ni][i];
          if (!full) x = (k0 + ni * 16 + l15 <= qr) ? x : -1e30f;
          e[ni] = __builtin_amdgcn_exp2f(x);   // P = 2^(score*log2e/8)
        }
        lrow[i] += (e[0] + e[1]) + (e[2] + e[3]);
        int prow = (quad * 4 + i) * 64;   // store col' = col ^ (quad*16)
        Pl[wave][prow + ((0 ^ quad) * 16 + l15)] = (bf16)e[0];
        Pl[wave][prow + ((1 ^ quad) * 16 + l15)] = (bf16)e[1];
        Pl[wave][prow + ((2 ^ quad) * 16 + l15)] = (bf16)e[2];
        Pl[wave][prow + ((3 ^ quad) * 16 + l15)] = (bf16)e[3];
      }
      asm volatile("s_waitcnt lgkmcnt(0)" ::: "memory");
      // PV: P[16x64] @ V[64x64]
#pragma unroll
      for (int kk = 0; kk < 2; ++kk) {
        int kbase = kk * 32 + quad * 8;
        bf16x8 pf = *(const bf16x8*)(&Pl[wave][l15 * 64 + (kbase ^ ((l15 >> 2) * 16))]);
#pragma unroll
        for (int ni = 0; ni < 4; ++ni) {
          int dd = ni * 16 + l15, u = kk * 4 + quad;
          bf16x8 vf = *(const bf16x8*)(&Vl[dd * 64 + ((u ^ (dd & 7)) * 8)]);
          oacc[ni] = __builtin_amdgcn_mfma_f32_16x16x32_bf16(pf, vf, oacc[ni], 0, 0, 0);
        }
      }
    }
    // epilogue: reduce l across the 16 q-columns group, write Y bf16
#pragma unroll
    for (int i = 0; i < 4; ++i) {
      float rs = lrow[i];
#pragma unroll
      for (int off = 8; off; off >>= 1) rs += __shfl_xor(rs, off, 16);
      float inv = 1.0f / rs;
      int qr = wq0 + quad * 4 + i;
      bf16* dst = Y + ((long)(b * SEQ + qr)) * EMB + h * HD;
#pragma unroll
      for (int ni = 0; ni < 4; ++ni)
        dst[ni * 16 + l15] = (bf16)(oacc[ni][i] * inv);
    }
  }
}

extern "C" void kernel_launch(void* const* d_in, const int* in_sizes, int n_in,
                              void* d_out, int out_size, void* d_ws, size_t ws_size,
                              hipStream_t stream) {
  const float* x      = (const float*)d_in[0];
  const float* W_attn = (const float*)d_in[1];
  const float* b_attn = (const float*)d_in[2];
  const float* W_proj = (const float*)d_in[3];
  const float* b_proj = (const float*)d_in[4];
  float* out = (float*)d_out;
  char* ws = (char*)d_ws;
  bf16* xb  = (bf16*)(ws);                 // 16.78 MB
  bf16* WaT = (bf16*)(ws + 16777216);      //  6.29 MB
  bf16* WpT = (bf16*)(ws + 23068672);      //  2.10 MB
  bf16* Qb  = (bf16*)(ws + 25165824);      // 16.78 MB (pre-scaled)
  bf16* Kb  = (bf16*)(ws + 41943040);      // 16.78 MB
  bf16* Vtb = (bf16*)(ws + 58720256);      // 16.78 MB (transposed [b,h,d,s])
  bf16* Yb  = (bf16*)(ws + 75497472);      // 16.78 MB

  cvt_f32_bf16<<<8192, 256, 0, stream>>>(x, xb, BATCH * SEQ * EMB);
  transpose_cvt<<<dim3(96, 32), 256, 0, stream>>>(W_attn, WaT, EMB, 3 * EMB);
  transpose_cvt<<<dim3(32, 32), 256, 0, stream>>>(W_proj, WpT, EMB, EMB);
  gemm_bt<<<dim3(24, 64), 256, 0, stream>>>(xb, WaT, b_attn, EMB, 3 * EMB, 0,
                                            Qb, Kb, Vtb, nullptr);
  attn<<<dim3(16, BATCH * NH), 256, 0, stream>>>(Qb, Kb, Vtb, Yb);
  gemm_bt<<<dim3(8, 64), 256, 0, stream>>>(Yb, WpT, b_proj, EMB, EMB, 1,
                                           nullptr, nullptr, nullptr, out);
}